// Round 3
// baseline (272.315 us; speedup 1.0000x reference)
//
#include <hip/hip_runtime.h>
#include <hip/hip_bf16.h>

#define BATCH 4096
#define TT 512
#define HH 64
#define BT 8       // batch rows per block; rows 4q,4q+1 of the 16-row tile are live
#define XS 516     // x_s row stride in floats
#define HS 72      // h buffer row stride in bf16

typedef __attribute__((ext_vector_type(8))) short short8;
typedef __attribute__((ext_vector_type(4))) float floatx4;
typedef __attribute__((ext_vector_type(2))) float float2v;

#define SGB __builtin_amdgcn_sched_group_barrier
// masks: VALU=0x2, MFMA=0x8, DS_READ=0x100

__device__ __forceinline__ unsigned short f2bf(float f) {   // RNE f32->bf16 (weights, one-time)
    unsigned u = __float_as_uint(f);
    u = u + 0x7FFFu + ((u >> 16) & 1u);
    return (unsigned short)(u >> 16);
}

// R18: in-order-issue fix. R15 wall 951 = matrix 310 + trans/VALU 505 + 136,
// strictly additive because each wave's stream is [8xMFMA][10xexp2]: in-order
// issue pins the wave feeding the matrix pipe at its accept rate, exps can't
// issue behind them; both co-resident waves do it in the same phase. R16/R17
// (wave-phase fixes) failed; the fix is per-wave EMISSION interleave:
// alternate [MFMA-pair t][exp-pair t] so every wave feeds matrix+trans
// concurrently — self-synchronizing, no offset persistence required.
// Source-order weave + sched_group_barrier pins inside each barrier-aligned
// region. Math identical to R15.
__global__ __launch_bounds__(256, 2) void lstm_kernel(
    const float* __restrict__ x, const float* __restrict__ W_ih,
    const float* __restrict__ W_hh, const float* __restrict__ b_ih,
    const float* __restrict__ b_hh, const float* __restrict__ W_out,
    const float* __restrict__ b_out, float* __restrict__ out)
{
    __shared__ __align__(16) float x_s[BT * XS];             // 16.5 KB
    __shared__ __align__(16) unsigned short hb0[16 * HS];    // h(k), k even; rows 4q+2,4q+3 stay 0
    __shared__ __align__(16) unsigned short hb1[16 * HS];    // h(k), k odd
    __shared__ __align__(16) float hf[BT * 65];

    const int tid = threadIdx.x;
    const int w = tid >> 6;       // wave 0..3 -> hidden slice [16w,16w+16)
    const int l = tid & 63;
    const int q = l >> 4;
    const int c = l & 15;
    const int n = 16 * w + c;     // hidden index this lane activates
    const int bbase = blockIdx.x * BT;

    // stage x[bbase..bbase+7][0..511] into LDS, coalesced float4
    for (int i = 0; i < 4; ++i) {
        int flat = i * 256 + tid;              // 1024 float4s
        int row = flat >> 7, c4 = flat & 127;
        const float4* xg = reinterpret_cast<const float4*>(x + (size_t)(bbase + row) * TT);
        float4 v = xg[c4];
        *reinterpret_cast<float4*>(&x_s[row * XS + c4 * 4]) = v;
    }
    for (int i = tid; i < 16 * HS; i += 256) { hb0[i] = 0; hb1[i] = 0; }

    const float L1 = 1.44269504089f;      // log2(e)
    const float L2 = 2.88539008178f;      // 2*log2(e)

    // persistent B-fragments, PRE-SCALED: t=0(i),1(f),3(o): -log2e ; t=2(g): +2log2e
    short8 bfr[4][2];
    float2v wih2[4], bb2[4];
    for (int t = 0; t < 4; ++t) {
        float sc = (t == 2) ? L2 : -L1;
        int g = 64 * t + n;
        float wv = W_ih[g] * sc;
        float bv = (b_ih[g] + b_hh[g]) * sc;
        wih2[t] = float2v{wv, wv};
        bb2[t] = float2v{bv, bv};
        for (int ks = 0; ks < 2; ++ks) {
            const float* wp = W_hh + g * 64 + ks * 32 + q * 8;
            short8 v;
            #pragma unroll
            for (int j = 0; j < 8; ++j) v[j] = (short)f2bf(wp[j] * sc);
            bfr[t][ks] = v;
        }
    }

    float2v cst2 = {0.f, 0.f};    // c-state, batch rows {2q, 2q+1}, hidden n
    float2v hv2 = {0.f, 0.f};
    const float2v one2 = {1.f, 1.f};
    const float2v L2v = {L2, L2};

    floatx4 acc[4];               // slots r=2,3 face zero A-rows: init once, stay 0
    #pragma unroll
    for (int t = 0; t < 4; ++t) acc[t] = floatx4{0.f, 0.f, 0.f, 0.f};

    const int aoff = c * HS + q * 8;      // A-frag LDS offset (shorts)
    const int woff = (4 * q) * HS + n;    // h write base; +HS for cell 1
    const float* xrowA = &x_s[(2 * q) * XS];
    const float* xrowB = &x_s[(2 * q + 1) * XS];

    __syncthreads();   // staging + zeroed h buffers visible

    float2v x01 = {xrowA[0], xrowB[0]};   // x(0)

    // one barrier-aligned body: frag reads -> INIT -> M/E weave -> algebra ->
    // h write -> x(k+1) hoist -> barrier. src holds h(k-1), dst receives h(k).
    auto body = [&](const unsigned short* src, unsigned short* dst, int k) {
        short8 a0 = *reinterpret_cast<const short8*>(src + aoff);
        short8 a1 = *reinterpret_cast<const short8*>(src + aoff + 32);

        // emission pins for this region: spread MFMA pairs between VALU packets
        SGB(0x100, 4, 0);                 // 2 frag reads + 2 x reads early
        SGB(0x2, 12, 0);                  // INIT (pk fma + inserts)
        SGB(0x8, 2, 0); SGB(0x2, 2, 0);   // M0 pair | E_i pair
        SGB(0x8, 2, 0); SGB(0x2, 2, 0);   // M1 pair | E_f pair
        SGB(0x8, 2, 0); SGB(0x2, 2, 0);   // M2 pair | E_g pair
        SGB(0x8, 2, 0);                   // M3 pair; rest unconstrained

        #pragma unroll
        for (int t = 0; t < 4; ++t) {
            float2v a2 = x01 * wih2[t] + bb2[t];
            acc[t][0] = a2.x; acc[t][1] = a2.y;
        }
        float2v ei2, ef2, eg2, eo2;
        // ---- M/E weave: exps of gate t trail MFMA pair t ----
        acc[0] = __builtin_amdgcn_mfma_f32_16x16x32_bf16(a0, bfr[0][0], acc[0], 0, 0, 0);
        acc[0] = __builtin_amdgcn_mfma_f32_16x16x32_bf16(a1, bfr[0][1], acc[0], 0, 0, 0);
        acc[1] = __builtin_amdgcn_mfma_f32_16x16x32_bf16(a0, bfr[1][0], acc[1], 0, 0, 0);
        acc[1] = __builtin_amdgcn_mfma_f32_16x16x32_bf16(a1, bfr[1][1], acc[1], 0, 0, 0);
        ei2.x = __builtin_amdgcn_exp2f(acc[0][0]);
        ei2.y = __builtin_amdgcn_exp2f(acc[0][1]);
        acc[2] = __builtin_amdgcn_mfma_f32_16x16x32_bf16(a0, bfr[2][0], acc[2], 0, 0, 0);
        acc[2] = __builtin_amdgcn_mfma_f32_16x16x32_bf16(a1, bfr[2][1], acc[2], 0, 0, 0);
        ef2.x = __builtin_amdgcn_exp2f(acc[1][0]);
        ef2.y = __builtin_amdgcn_exp2f(acc[1][1]);
        acc[3] = __builtin_amdgcn_mfma_f32_16x16x32_bf16(a0, bfr[3][0], acc[3], 0, 0, 0);
        acc[3] = __builtin_amdgcn_mfma_f32_16x16x32_bf16(a1, bfr[3][1], acc[3], 0, 0, 0);
        eg2.x = __builtin_amdgcn_exp2f(acc[2][0]);
        eg2.y = __builtin_amdgcn_exp2f(acc[2][1]);
        eo2.x = __builtin_amdgcn_exp2f(acc[3][0]);
        eo2.y = __builtin_amdgcn_exp2f(acc[3][1]);
        // ---- activation algebra (identical to R15) ----
        float2v pf2 = ef2 + one2;
        float2v pg2 = (ei2 + one2) * (eg2 + one2);
        float2v d2 = pf2 * pg2;
        float rd = __builtin_amdgcn_rcpf(d2.x * d2.y);
        float2v num2 = cst2 * pg2 + (eg2 - one2) * pf2;
        float2v dsw = {d2.y, d2.x};
        cst2 = num2 * dsw * rd;
        float2v l2c = cst2 * L2v;
        float2v ec2;
        ec2.x = __builtin_amdgcn_exp2f(l2c.x);
        ec2.y = __builtin_amdgcn_exp2f(l2c.y);
        float2v e2 = (eo2 + one2) * (ec2 + one2);
        float re = __builtin_amdgcn_rcpf(e2.x * e2.y);
        float2v esw = {e2.y, e2.x};
        hv2 = (ec2 - one2) * esw * re;
        // h(k) -> LDS (one v_cvt_pk_bf16_f32)
        __hip_bfloat162 hpk = __float22bfloat162_rn(float2{hv2.x, hv2.y});
        dst[woff]      = *reinterpret_cast<unsigned short*>(&hpk.x);
        dst[woff + HS] = *reinterpret_cast<unsigned short*>(&hpk.y);
        // hoist x(k+1): crosses the barrier, latency fully hidden
        x01 = float2v{xrowA[k + 1], xrowB[k + 1]};
        __syncthreads();
    };

    // k=0 reads zeroed hb1 (h(-1)=0) -> gates(0)=x_proj, matching reference
    for (int k = 0; k < 510; k += 2) {
        body(hb1, hb0, k);         // even k: src h(k-1) in hb1, dst hb0
        body(hb0, hb1, k + 1);     // odd  k
    }
    body(hb1, hb0, 510);           // writes h(510), loads x(511)

    // ---- tail: step 511 (no h write, no barrier) ----
    {
        short8 a0 = *reinterpret_cast<const short8*>(hb0 + aoff);
        short8 a1 = *reinterpret_cast<const short8*>(hb0 + aoff + 32);
        #pragma unroll
        for (int t = 0; t < 4; ++t) {
            float2v a2 = x01 * wih2[t] + bb2[t];
            acc[t][0] = a2.x; acc[t][1] = a2.y;
        }
        #pragma unroll
        for (int t = 0; t < 4; ++t) {
            acc[t] = __builtin_amdgcn_mfma_f32_16x16x32_bf16(a0, bfr[t][0], acc[t], 0, 0, 0);
            acc[t] = __builtin_amdgcn_mfma_f32_16x16x32_bf16(a1, bfr[t][1], acc[t], 0, 0, 0);
        }
        float2v ei2, ef2, eg2, eo2;
        ei2.x = __builtin_amdgcn_exp2f(acc[0][0]);
        ei2.y = __builtin_amdgcn_exp2f(acc[0][1]);
        ef2.x = __builtin_amdgcn_exp2f(acc[1][0]);
        ef2.y = __builtin_amdgcn_exp2f(acc[1][1]);
        eg2.x = __builtin_amdgcn_exp2f(acc[2][0]);
        eg2.y = __builtin_amdgcn_exp2f(acc[2][1]);
        eo2.x = __builtin_amdgcn_exp2f(acc[3][0]);
        eo2.y = __builtin_amdgcn_exp2f(acc[3][1]);
        float2v pf2 = ef2 + one2;
        float2v pg2 = (ei2 + one2) * (eg2 + one2);
        float2v d2 = pf2 * pg2;
        float rd = __builtin_amdgcn_rcpf(d2.x * d2.y);
        float2v num2 = cst2 * pg2 + (eg2 - one2) * pf2;
        float2v dsw = {d2.y, d2.x};
        cst2 = num2 * dsw * rd;
        float2v l2c = cst2 * L2v;
        float2v ec2;
        ec2.x = __builtin_amdgcn_exp2f(l2c.x);
        ec2.y = __builtin_amdgcn_exp2f(l2c.y);
        float2v e2 = (eo2 + one2) * (ec2 + one2);
        float re = __builtin_amdgcn_rcpf(e2.x * e2.y);
        float2v esw = {e2.y, e2.x};
        hv2 = (ec2 - one2) * esw * re;
    }

    hf[(2 * q) * 65 + n] = hv2.x;
    hf[(2 * q + 1) * 65 + n] = hv2.y;
    __syncthreads();

    // head: out[b][o] = sum_n hf[b][n]*W_out[o][n] + b_out[o]
    if (tid < BT * 3) {
        int row = tid / 3, o = tid % 3;
        float s = b_out[o];
        #pragma unroll 8
        for (int k = 0; k < HH; ++k) s = fmaf(hf[row * 65 + k], W_out[o * 64 + k], s);
        out[(size_t)(bbase + row) * 3 + o] = s;
    }
}

extern "C" void kernel_launch(void* const* d_in, const int* in_sizes, int n_in,
                              void* d_out, int out_size, void* d_ws, size_t ws_size,
                              hipStream_t stream) {
    const float* x     = (const float*)d_in[0];
    const float* W_ih  = (const float*)d_in[1];
    const float* W_hh  = (const float*)d_in[2];
    const float* b_ih  = (const float*)d_in[3];
    const float* b_hh  = (const float*)d_in[4];
    const float* W_out = (const float*)d_in[5];
    const float* b_out = (const float*)d_in[6];
    float* out = (float*)d_out;
    hipLaunchKernelGGL(lstm_kernel, dim3(BATCH / BT), dim3(256), 0, stream,
                       x, W_ih, W_hh, b_ih, b_hh, W_out, b_out, out);
}